// Round 3
// baseline (113.244 us; speedup 1.0000x reference)
//
#include <hip/hip_runtime.h>
#include <math.h>

// ---------------- problem constants ----------------
#define N_TOTAL 2097152
#define WINDOW  20
#define M_ROLL  (N_TOTAL - WINDOW)      // 2097132 rolling windows
#define K_CVAR  62914u                  // int(N * 0.03)

// ---------------- kernel config --------------------
#define BS      256
#define TILE    1024                    // elements per block (4 per thread)
#define NB_MAIN (N_TOTAL / TILE)        // 2048 blocks
#define NBINS   1024                    // sign + 8 exp + 1 mantissa bit (u >> 22)
#define CB      1024                    // combine block size

#define FPSCALE     2097152.0f          // 2^21 fixed-point scale for bin sums
#define INV_FPSCALE (1.0 / 2097152.0)

// ---------------- ws layout (bytes) ----------------
// acc doubles: 0..6 = S1..S7 (sum r, sum r^2, sum|r|, #r>0, sum|dr|, sum signprod, sum|ds|)
//              7 = sum vol, 8 = sum vol^2
#define ACC_OFF  0                      // double[9] (padded to 128)
#define HCNT_OFF 128                    // uint[1024]
#define HSUM_OFF 4224                   // long long[1024] (fixed-point sums)
#define DDT_OFF  12416                  // float4[2048] (fully overwritten, no init)
#define ZERO_BYTES 12416

__device__ __forceinline__ unsigned ordkey(float f) {
    unsigned b = __float_as_uint(f);
    return (b & 0x80000000u) ? ~b : (b | 0x80000000u);
}
__device__ __forceinline__ float inv_ordkey(unsigned u) {
    return __uint_as_float((u & 0x80000000u) ? (u ^ 0x80000000u) : ~u);
}
__device__ __forceinline__ float sgnf(float x) {
    return (x > 0.f) ? 1.f : ((x < 0.f) ? -1.f : 0.f);
}
// tanh(x) = sign(x) * (1 - 2/(e^{2|x|}+1)); abs error ~2e-7, overflow-safe.
__device__ __forceinline__ float fast_tanh(float x) {
    float ax = fabsf(x);
    float e = __expf(2.0f * ax);
    float t = 1.0f - 2.0f * __builtin_amdgcn_rcpf(e + 1.0f);
    return copysignf(t, x);
}

// ============ main fused pass: one sweep does everything =====================
__global__ __launch_bounds__(BS, 6) void k_main(const float* __restrict__ pred,
                                                const float* __restrict__ ret,
                                                double* __restrict__ acc,
                                                unsigned* __restrict__ hcnt,
                                                unsigned long long* __restrict__ hsum,
                                                float4* __restrict__ ddt)
{
    __shared__ __align__(16) float sh_r[TILE + 24];  // r for g in [tileStart-4, tileStart+TILE+20)
    __shared__ __align__(16) float sh_s[TILE + 8];   // signals, left halo only
    __shared__ unsigned lc[NBINS];
    __shared__ int      ls[NBINS];
    __shared__ float sred[4][9];
    __shared__ float4 stup[4];

    const int tid = threadIdx.x;
    const int tileStart = blockIdx.x * TILE;
    const int t4 = tid * 4;

    for (int b = tid; b < NBINS; b += BS) { lc[b] = 0u; ls[b] = 0; }

    // ---- stage own chunk (float4, aligned) ----
    float4 p4 = *(const float4*)(pred + tileStart + t4);
    float4 q4 = *(const float4*)(ret  + tileStart + t4);
    float sg0 = fast_tanh(p4.x), sg1 = fast_tanh(p4.y);
    float sg2 = fast_tanh(p4.z), sg3 = fast_tanh(p4.w);
    float rr0 = q4.x * sg0, rr1 = q4.y * sg1, rr2 = q4.z * sg2, rr3 = q4.w * sg3;
    *(float4*)&sh_r[4 + t4] = make_float4(rr0, rr1, rr2, rr3);
    *(float4*)&sh_s[4 + t4] = make_float4(sg0, sg1, sg2, sg3);

    // ---- halo: tid 0 -> left 4, tid 1..5 -> right 20 ----
    if (tid < 6) {
        int k = (tid == 0) ? 0 : (TILE + 4 * tid);   // 0, TILE+4 .. TILE+20
        int g = tileStart + k - 4;
        float4 hp = make_float4(0.f, 0.f, 0.f, 0.f), hq = hp;
        if (g >= 0 && g + 3 < N_TOTAL) {
            hp = *(const float4*)(pred + g);
            hq = *(const float4*)(ret + g);
        }
        float h0 = fast_tanh(hp.x), h1 = fast_tanh(hp.y);
        float h2 = fast_tanh(hp.z), h3 = fast_tanh(hp.w);
        *(float4*)&sh_r[k] = make_float4(hq.x * h0, hq.y * h1, hq.z * h2, hq.w * h3);
        if (tid == 0) *(float4*)&sh_s[0] = make_float4(h0, h1, h2, h3);
    }
    __syncthreads();

    const int k0 = 4 + t4;
    const int iBase = tileStart + t4;

    // neighbor values needed beyond own registers
    float4 wv1 = *(float4*)&sh_r[k0 + 4];
    float4 wv2 = *(float4*)&sh_r[k0 + 8];
    float4 wv3 = *(float4*)&sh_r[k0 + 12];
    float4 wv4 = *(float4*)&sh_r[k0 + 16];
    float4 wv5 = *(float4*)&sh_r[k0 + 20];
    float rm1 = sh_r[k0 - 1];
    float sm1 = sh_s[k0 - 1];

    // ---- elementwise sums ----
    float sum_r  = rr0 + rr1 + rr2 + rr3;
    float sum_r2 = rr0*rr0 + rr1*rr1 + rr2*rr2 + rr3*rr3;
    float sum_ab = fabsf(rr0) + fabsf(rr1) + fabsf(rr2) + fabsf(rr3);
    float cnt_p  = ((rr0 > 0.f) ? 1.f : 0.f) + ((rr1 > 0.f) ? 1.f : 0.f)
                 + ((rr2 > 0.f) ? 1.f : 0.f) + ((rr3 > 0.f) ? 1.f : 0.f);
    float sum_adr = fabsf(rr1 - rr0) + fabsf(rr2 - rr1) + fabsf(rr3 - rr2);
    float sum_sgn = sgnf(rr1)*sgnf(rr0) + sgnf(rr2)*sgnf(rr1) + sgnf(rr3)*sgnf(rr2);
    float sum_ads = fabsf(sg1 - sg0) + fabsf(sg2 - sg1) + fabsf(sg3 - sg2);
    if (iBase >= 1) {
        sum_adr += fabsf(rr0 - rm1);
        sum_sgn += sgnf(rr0) * sgnf(rm1);
        sum_ads += fabsf(sg0 - sm1);
    }

    // ---- histogram (native int LDS atomics; counts + fixed-point sums) ----
    {
        unsigned u0 = ordkey(rr0) >> 22, u1 = ordkey(rr1) >> 22;
        unsigned u2 = ordkey(rr2) >> 22, u3 = ordkey(rr3) >> 22;
        atomicAdd(&lc[u0], 1u); atomicAdd(&ls[(int)u0], __float2int_rn(rr0 * FPSCALE));
        atomicAdd(&lc[u1], 1u); atomicAdd(&ls[(int)u1], __float2int_rn(rr1 * FPSCALE));
        atomicAdd(&lc[u2], 1u); atomicAdd(&ls[(int)u2], __float2int_rn(rr2 * FPSCALE));
        atomicAdd(&lc[u3], 1u); atomicAdd(&ls[(int)u3], __float2int_rn(rr3 * FPSCALE));
    }

    // ---- rolling-vol: base 20-window + 3 slides (covers a[0..22]) ----
    float vsum = 0.f, vsqr = 0.f;
    {
        float ws = sum_r;
        float wq = sum_r2;
        ws += wv1.x + wv1.y + wv1.z + wv1.w;
        wq += wv1.x*wv1.x + wv1.y*wv1.y + wv1.z*wv1.z + wv1.w*wv1.w;
        ws += wv2.x + wv2.y + wv2.z + wv2.w;
        wq += wv2.x*wv2.x + wv2.y*wv2.y + wv2.z*wv2.z + wv2.w*wv2.w;
        ws += wv3.x + wv3.y + wv3.z + wv3.w;
        wq += wv3.x*wv3.x + wv3.y*wv3.y + wv3.z*wv3.z + wv3.w*wv3.w;
        ws += wv4.x + wv4.y + wv4.z + wv4.w;
        wq += wv4.x*wv4.x + wv4.y*wv4.y + wv4.z*wv4.z + wv4.w*wv4.w;

        if (iBase + 0 < M_ROLL) {
            float var = fmaxf((wq - ws*ws*(1.0f/WINDOW)) * (1.0f/(WINDOW-1)), 0.f);
            vsum += sqrtf(var); vsqr += var;
        }
        ws += wv5.x - rr0; wq += wv5.x*wv5.x - rr0*rr0;
        if (iBase + 1 < M_ROLL) {
            float var = fmaxf((wq - ws*ws*(1.0f/WINDOW)) * (1.0f/(WINDOW-1)), 0.f);
            vsum += sqrtf(var); vsqr += var;
        }
        ws += wv5.y - rr1; wq += wv5.y*wv5.y - rr1*rr1;
        if (iBase + 2 < M_ROLL) {
            float var = fmaxf((wq - ws*ws*(1.0f/WINDOW)) * (1.0f/(WINDOW-1)), 0.f);
            vsum += sqrtf(var); vsqr += var;
        }
        ws += wv5.z - rr2; wq += wv5.z*wv5.z - rr2*rr2;
        if (iBase + 3 < M_ROLL) {
            float var = fmaxf((wq - ws*ws*(1.0f/WINDOW)) * (1.0f/(WINDOW-1)), 0.f);
            vsum += sqrtf(var); vsqr += var;
        }
    }

    // ---- drawdown tuple over own 4 contiguous elements (in order) ----
    float tS = rr0, tMP = rr0, tMN = rr0, tDD = 0.f;
    tS += rr1; tMP = fmaxf(tMP, tS); tMN = fminf(tMN, tS); tDD = fmaxf(tDD, tMP - tS);
    tS += rr2; tMP = fmaxf(tMP, tS); tMN = fminf(tMN, tS); tDD = fmaxf(tDD, tMP - tS);
    tS += rr3; tMP = fmaxf(tMP, tS); tMN = fminf(tMN, tS); tDD = fmaxf(tDD, tMP - tS);

    // ---- wave-level ordered fold (ascending offsets keep segment order) ----
    for (int off = 1; off < 64; off <<= 1) {
        float oS  = __shfl_down(tS,  off);
        float oMP = __shfl_down(tMP, off);
        float oMN = __shfl_down(tMN, off);
        float oDD = __shfl_down(tDD, off);
        float nDD = fmaxf(fmaxf(tDD, oDD), tMP - (tS + oMN));
        float nMP = fmaxf(tMP, tS + oMP);
        float nMN = fminf(tMN, tS + oMN);
        tS += oS; tMP = nMP; tMN = nMN; tDD = nDD;
    }
    // ---- wave-level sum reduce for the 9 scalar accumulators ----
    for (int off = 1; off < 64; off <<= 1) {
        sum_r  += __shfl_down(sum_r,  off); sum_r2 += __shfl_down(sum_r2, off);
        sum_ab += __shfl_down(sum_ab, off); cnt_p  += __shfl_down(cnt_p,  off);
        sum_adr+= __shfl_down(sum_adr,off); sum_sgn+= __shfl_down(sum_sgn,off);
        sum_ads+= __shfl_down(sum_ads,off); vsum   += __shfl_down(vsum,   off);
        vsqr   += __shfl_down(vsqr,   off);
    }
    int wv = tid >> 6;
    if ((tid & 63) == 0) {
        sred[wv][0]=sum_r;  sred[wv][1]=sum_r2; sred[wv][2]=sum_ab;
        sred[wv][3]=cnt_p;  sred[wv][4]=sum_adr; sred[wv][5]=sum_sgn;
        sred[wv][6]=sum_ads; sred[wv][7]=vsum;   sred[wv][8]=vsqr;
        stup[wv] = make_float4(tS, tMP, tMN, tDD);
    }
    __syncthreads();

    if (tid < 9) {
        float tot = sred[0][tid] + sred[1][tid] + sred[2][tid] + sred[3][tid];
        atomicAdd(&acc[tid], (double)tot);
    }
    if (tid == 0) {
        float4 a = stup[0];
        for (int w = 1; w < 4; ++w) {
            float4 b = stup[w];
            float nDD = fmaxf(fmaxf(a.w, b.w), a.y - (a.x + b.z));
            float nMP = fmaxf(a.y, a.x + b.y);
            float nMN = fminf(a.z, a.x + b.z);
            a.x += b.x; a.y = nMP; a.z = nMN; a.w = nDD;
        }
        ddt[blockIdx.x] = a;
    }
    for (int b = tid; b < NBINS; b += BS) {
        unsigned c = lc[b];
        if (c) {
            atomicAdd(&hcnt[b], c);
            atomicAdd(&hsum[b], (unsigned long long)(long long)ls[b]);
        }
    }
}

// ============ combine: drawdown tree + hist scan + CVaR + final formula ======
__global__ __launch_bounds__(CB) void k_combine(const double* __restrict__ acc,
                                                const unsigned* __restrict__ hcnt,
                                                const unsigned long long* __restrict__ hsum,
                                                const float4* __restrict__ ddt,
                                                float* __restrict__ out)
{
    __shared__ double dS[CB], dMP[CB], dMN[CB], dDD[CB];
    __shared__ unsigned scn[CB];
    __shared__ int s_edge;
    __shared__ unsigned s_cbelow, s_ce;

    const int t = threadIdx.x;

    // ---- A: drawdown ordered tree (double); fold 2 tuples per thread ----
    float4 a = ddt[2 * t], b = ddt[2 * t + 1];
    double S = a.x, MP = a.y, MN = a.z, DD = a.w;
    {
        double nDD = fmax(fmax(DD, (double)b.w), MP - (S + (double)b.z));
        double nMP = fmax(MP, S + (double)b.y);
        double nMN = fmin(MN, S + (double)b.z);
        S += (double)b.x; MP = nMP; MN = nMN; DD = nDD;
    }
    dS[t] = S; dMP[t] = MP; dMN[t] = MN; dDD[t] = DD;
    __syncthreads();
    for (int off = 1; off < CB; off <<= 1) {
        if ((t & (2 * off - 1)) == 0) {
            double aS=dS[t], aMP=dMP[t], aMN=dMN[t], aDD=dDD[t];
            double bS=dS[t+off], bMP=dMP[t+off], bMN=dMN[t+off], bDD=dDD[t+off];
            dDD[t] = fmax(fmax(aDD, bDD), aMP - (aS + bMN));
            dMP[t] = fmax(aMP, aS + bMP);
            dMN[t] = fmin(aMN, aS + bMN);
            dS[t]  = aS + bS;
        }
        __syncthreads();
    }
    // dDD[0] holds global max drawdown (preserved below)

    // ---- B: histogram scan (1 bin per thread) ----
    unsigned cnt = hcnt[t];
    long long hs = (long long)hsum[t];
    scn[t] = cnt;
    __syncthreads();
    for (int off = 1; off < CB; off <<= 1) {
        unsigned y = (t >= off) ? scn[t - off] : 0u;
        __syncthreads();
        scn[t] += y;
        __syncthreads();
    }
    unsigned incl = scn[t], excl = incl - cnt;
    if (excl < K_CVAR && incl >= K_CVAR) { s_edge = t; s_cbelow = excl; s_ce = cnt; }
    __syncthreads();
    const int be = s_edge;
    const unsigned cb = s_cbelow, ce = s_ce;

    // ---- C: sum of fixed-point bin sums strictly below the edge bin ----
    dS[t] = (t < be) ? (double)hs * INV_FPSCALE : 0.0;
    __syncthreads();
    for (int off = CB / 2; off >= 1; off >>= 1) {
        if (t < off) dS[t] += dS[t + off];
        __syncthreads();
    }

    if (t == 0) {
        double n = (double)N_TOTAL;
        double S1 = acc[0], S2 = acc[1], S3 = acc[2], S4 = acc[3];
        double S5 = acc[4], S6 = acc[5], S7 = acc[6], V1 = acc[7], V2 = acc[8];

        double mean_r = S1 / n;
        double var_r = (S2 - S1 * S1 / n) / (n - 1.0);
        if (var_r < 0.0) var_r = 0.0;
        double std_r = sqrt(var_r) + 1e-8;
        double base_sharpe = mean_r / std_r;

        double m = (double)M_ROLL;
        double var_v = (V2 - V1 * V1 / m) / (m - 1.0);
        if (var_v < 0.0) var_v = 0.0;
        double vs = 1.0 / (sqrt(var_v) + 1e-6);
        double es = base_sharpe * (1.0 + 0.1 * vs);

        double rm = S3 / n;
        double pf = S4 / n;
        double rs = 1.0 / (S5 / (n - 1.0) + 1e-6);
        double mc = S6 / (n - 1.0);
        double dd = fmax(dDD[0], 0.0);
        double ddp = dd - 0.05; if (ddp < 0.0) ddp = 0.0;
        double sc = S7 / (n - 1.0);
        double ss = 1.0 / (sc + 1e-6);

        // CVaR: full bins below edge + interpolated draw from the edge bin
        double bsum = dS[0];
        double mneed = (double)(K_CVAR - cb);
        double elo = (double)inv_ordkey(((unsigned)be) << 22);
        double ehi = (double)inv_ordkey(((unsigned)(be + 1)) << 22);
        double edgev = elo + (mneed / (2.0 * (double)(ce > 0u ? ce : 1u))) * (ehi - elo);
        double cvar = -(bsum + mneed * edgev) / (double)K_CVAR;

        double SC = 0.4 * es + 0.25 * rm + 0.15 * pf + 0.1 * mc + 0.05 * rs + 0.05 * ss;
        double RP = 0.05 * cvar + 0.02 * ddp + 0.01 * sc;
        out[0] = (float)(-(0.6 * rm + 0.4 * SC - RP));
    }
}

// ============ launch =========================================================
extern "C" void kernel_launch(void* const* d_in, const int* in_sizes, int n_in,
                              void* d_out, int out_size, void* d_ws, size_t ws_size,
                              hipStream_t stream)
{
    const float* pred = (const float*)d_in[0];
    const float* ret  = (const float*)d_in[1];
    char* ws = (char*)d_ws;
    double*             acc  = (double*)(ws + ACC_OFF);
    unsigned*           hcnt = (unsigned*)(ws + HCNT_OFF);
    unsigned long long* hsum = (unsigned long long*)(ws + HSUM_OFF);
    float4*             ddt  = (float4*)(ws + DDT_OFF);

    hipMemsetAsync(ws, 0, ZERO_BYTES, stream);
    k_main<<<NB_MAIN, BS, 0, stream>>>(pred, ret, acc, hcnt, hsum, ddt);
    k_combine<<<1, CB, 0, stream>>>(acc, hcnt, hsum, ddt, (float*)d_out);
}

// Round 4
// 87.796 us; speedup vs baseline: 1.2899x; 1.2899x over previous
//
#include <hip/hip_runtime.h>
#include <math.h>

// ---------------- problem constants ----------------
#define N_TOTAL 2097152
#define WINDOW  20
#define M_ROLL  (N_TOTAL - WINDOW)      // 2097132 rolling windows
#define K_CVAR  62914u                  // int(N * 0.03)

// ---------------- kernel config --------------------
#define BS      512                     // 8 waves/block
#define TILE    2048                    // elements per tile (4 per thread)
#define TPB     4                       // tiles per block (contiguous span)
#define SPAN    (TILE * TPB)            // 8192 elements per block
#define NB_MAIN (N_TOTAL / SPAN)        // 256 blocks (1 per CU)
#define NBINS   1024                    // sign + 8 exp + 1 mantissa bit (u >> 22)
#define CB      1024                    // combine block size

#define FPSCALE     2097152.0f          // 2^21 fixed-point scale
#define INV_FPSCALE (1.0 / 2097152.0)
#define CNT_SHIFT   42                  // count field in packed u64

// ---------------- ws layout (bytes) ----------------
// acc doubles: 0..6 = S1..S7 (sum r, sum r^2, sum|r|, #r>0, sum|dr|, sum signprod, sum|ds|)
//              7 = sum vol, 8 = sum vol^2
#define ACC_OFF  0                      // double[9] (padded to 128)
#define HG_OFF   128                    // u64[1024]: (count<<42) + sum((r+0.5)*2^21)
#define DDT_OFF  8320                   // double[4*256] drawdown tuples (fully overwritten)
#define ZERO_BYTES 8320

__device__ __forceinline__ unsigned ordkey(float f) {
    unsigned b = __float_as_uint(f);
    return (b & 0x80000000u) ? ~b : (b | 0x80000000u);
}
__device__ __forceinline__ float inv_ordkey(unsigned u) {
    return __uint_as_float((u & 0x80000000u) ? (u ^ 0x80000000u) : ~u);
}
__device__ __forceinline__ float sgnf(float x) {
    return (x > 0.f) ? 1.f : ((x < 0.f) ? -1.f : 0.f);
}
// tanh(x) = sign(x) * (1 - 2/(e^{2|x|}+1)); abs error ~2e-7, overflow-safe.
__device__ __forceinline__ float fast_tanh(float x) {
    float ax = fabsf(x);
    float e = __expf(2.0f * ax);
    float t = 1.0f - 2.0f * __builtin_amdgcn_rcpf(e + 1.0f);
    return copysignf(t, x);
}
// packed histogram contribution: exact count in high bits, biased fixed-point sum low
__device__ __forceinline__ unsigned long long encode_r(float r) {
    float fv = fminf(fmaxf(r + 0.5f, 0.f), 0.9999995f);
    return (1ull << CNT_SHIFT) | (unsigned long long)(unsigned)__float2int_rn(fv * FPSCALE);
}

// ============ main fused pass: 256 persistent blocks, 4 tiles each ===========
__global__ __launch_bounds__(BS, 2) void k_main(const float* __restrict__ pred,
                                                const float* __restrict__ ret,
                                                double* __restrict__ acc,
                                                unsigned long long* __restrict__ hg,
                                                double* __restrict__ ddt)
{
    __shared__ __align__(16) float sh_r[TILE + 24];  // r for [tileStart-4, tileStart+TILE+20)
    __shared__ __align__(16) float sh_s[TILE + 8];   // signals, left halo only
    __shared__ unsigned long long lh[NBINS];
    __shared__ float sred[8][9];
    __shared__ float4 stup[8];

    const int tid = threadIdx.x;
    const int blockStart = blockIdx.x * SPAN;
    const int t4 = tid * 4;

    for (int b = tid; b < NBINS; b += BS) lh[b] = 0ull;

    // persistent per-thread accumulators
    float sum_r = 0.f, sum_r2 = 0.f, sum_ab = 0.f, cnt_p = 0.f;
    float sum_adr = 0.f, sum_sgn = 0.f, sum_ads = 0.f, vsum = 0.f, vsqr = 0.f;
    // running block drawdown tuple (tid 0 only, double)
    double bS = 0.0, bMP = 0.0, bMN = 0.0, bDD = 0.0;

    // prefetch first tile
    float4 p4 = *(const float4*)(pred + blockStart + t4);
    float4 q4 = *(const float4*)(ret  + blockStart + t4);

    for (int tt = 0; tt < TPB; ++tt) {
        const int tileStart = blockStart + tt * TILE;

        // ---- stage own chunk ----
        float sg0 = fast_tanh(p4.x), sg1 = fast_tanh(p4.y);
        float sg2 = fast_tanh(p4.z), sg3 = fast_tanh(p4.w);
        float rr0 = q4.x * sg0, rr1 = q4.y * sg1, rr2 = q4.z * sg2, rr3 = q4.w * sg3;
        *(float4*)&sh_r[4 + t4] = make_float4(rr0, rr1, rr2, rr3);
        *(float4*)&sh_s[4 + t4] = make_float4(sg0, sg1, sg2, sg3);

        // ---- halo: tid 0 -> left 4, tid 1..5 -> right 20 ----
        if (tid < 6) {
            int k = (tid == 0) ? 0 : (TILE + 4 * tid);   // 0, TILE+4 .. TILE+20
            int g = tileStart + k - 4;
            float4 hp = make_float4(0.f, 0.f, 0.f, 0.f), hq = hp;
            if (g >= 0 && g + 3 < N_TOTAL) {
                hp = *(const float4*)(pred + g);
                hq = *(const float4*)(ret + g);
            }
            float h0 = fast_tanh(hp.x), h1 = fast_tanh(hp.y);
            float h2 = fast_tanh(hp.z), h3 = fast_tanh(hp.w);
            *(float4*)&sh_r[k] = make_float4(hq.x * h0, hq.y * h1, hq.z * h2, hq.w * h3);
            if (tid == 0) *(float4*)&sh_s[0] = make_float4(h0, h1, h2, h3);
        }
        __syncthreads();   // B1: staging complete

        // ---- prefetch next tile (overlaps compute below) ----
        if (tt + 1 < TPB) {
            p4 = *(const float4*)(pred + tileStart + TILE + t4);
            q4 = *(const float4*)(ret  + tileStart + TILE + t4);
        }

        const int k0 = 4 + t4;
        const int iBase = tileStart + t4;

        float4 wv1 = *(float4*)&sh_r[k0 + 4];
        float4 wv2 = *(float4*)&sh_r[k0 + 8];
        float4 wv3 = *(float4*)&sh_r[k0 + 12];
        float4 wv4 = *(float4*)&sh_r[k0 + 16];
        float4 wv5 = *(float4*)&sh_r[k0 + 20];
        float rm1 = sh_r[k0 - 1];
        float sm1 = sh_s[k0 - 1];

        // ---- elementwise sums ----
        float t_r  = rr0 + rr1 + rr2 + rr3;
        float t_r2 = rr0*rr0 + rr1*rr1 + rr2*rr2 + rr3*rr3;
        sum_r  += t_r;
        sum_r2 += t_r2;
        sum_ab += fabsf(rr0) + fabsf(rr1) + fabsf(rr2) + fabsf(rr3);
        cnt_p  += ((rr0 > 0.f) ? 1.f : 0.f) + ((rr1 > 0.f) ? 1.f : 0.f)
                + ((rr2 > 0.f) ? 1.f : 0.f) + ((rr3 > 0.f) ? 1.f : 0.f);
        sum_adr += fabsf(rr1 - rr0) + fabsf(rr2 - rr1) + fabsf(rr3 - rr2);
        sum_sgn += sgnf(rr1)*sgnf(rr0) + sgnf(rr2)*sgnf(rr1) + sgnf(rr3)*sgnf(rr2);
        sum_ads += fabsf(sg1 - sg0) + fabsf(sg2 - sg1) + fabsf(sg3 - sg2);
        if (iBase >= 1) {
            sum_adr += fabsf(rr0 - rm1);
            sum_sgn += sgnf(rr0) * sgnf(rm1);
            sum_ads += fabsf(sg0 - sm1);
        }

        // ---- histogram: one packed u64 LDS atomic per element ----
        atomicAdd(&lh[ordkey(rr0) >> 22], encode_r(rr0));
        atomicAdd(&lh[ordkey(rr1) >> 22], encode_r(rr1));
        atomicAdd(&lh[ordkey(rr2) >> 22], encode_r(rr2));
        atomicAdd(&lh[ordkey(rr3) >> 22], encode_r(rr3));

        // ---- rolling-vol: base 20-window + 3 slides ----
        {
            float ws = t_r, wq = t_r2;
            ws += wv1.x + wv1.y + wv1.z + wv1.w;
            wq += wv1.x*wv1.x + wv1.y*wv1.y + wv1.z*wv1.z + wv1.w*wv1.w;
            ws += wv2.x + wv2.y + wv2.z + wv2.w;
            wq += wv2.x*wv2.x + wv2.y*wv2.y + wv2.z*wv2.z + wv2.w*wv2.w;
            ws += wv3.x + wv3.y + wv3.z + wv3.w;
            wq += wv3.x*wv3.x + wv3.y*wv3.y + wv3.z*wv3.z + wv3.w*wv3.w;
            ws += wv4.x + wv4.y + wv4.z + wv4.w;
            wq += wv4.x*wv4.x + wv4.y*wv4.y + wv4.z*wv4.z + wv4.w*wv4.w;

            if (iBase + 0 < M_ROLL) {
                float var = fmaxf((wq - ws*ws*(1.0f/WINDOW)) * (1.0f/(WINDOW-1)), 0.f);
                vsum += sqrtf(var); vsqr += var;
            }
            ws += wv5.x - rr0; wq += wv5.x*wv5.x - rr0*rr0;
            if (iBase + 1 < M_ROLL) {
                float var = fmaxf((wq - ws*ws*(1.0f/WINDOW)) * (1.0f/(WINDOW-1)), 0.f);
                vsum += sqrtf(var); vsqr += var;
            }
            ws += wv5.y - rr1; wq += wv5.y*wv5.y - rr1*rr1;
            if (iBase + 2 < M_ROLL) {
                float var = fmaxf((wq - ws*ws*(1.0f/WINDOW)) * (1.0f/(WINDOW-1)), 0.f);
                vsum += sqrtf(var); vsqr += var;
            }
            ws += wv5.z - rr2; wq += wv5.z*wv5.z - rr2*rr2;
            if (iBase + 3 < M_ROLL) {
                float var = fmaxf((wq - ws*ws*(1.0f/WINDOW)) * (1.0f/(WINDOW-1)), 0.f);
                vsum += sqrtf(var); vsqr += var;
            }
        }

        // ---- drawdown tuple: own 4 elements, then wave ordered fold ----
        float tS = rr0, tMP = rr0, tMN = rr0, tDD = 0.f;
        tS += rr1; tMP = fmaxf(tMP, tS); tMN = fminf(tMN, tS); tDD = fmaxf(tDD, tMP - tS);
        tS += rr2; tMP = fmaxf(tMP, tS); tMN = fminf(tMN, tS); tDD = fmaxf(tDD, tMP - tS);
        tS += rr3; tMP = fmaxf(tMP, tS); tMN = fminf(tMN, tS); tDD = fmaxf(tDD, tMP - tS);
        for (int off = 1; off < 64; off <<= 1) {
            float oS  = __shfl_down(tS,  off);
            float oMP = __shfl_down(tMP, off);
            float oMN = __shfl_down(tMN, off);
            float oDD = __shfl_down(tDD, off);
            float nDD = fmaxf(fmaxf(tDD, oDD), tMP - (tS + oMN));
            float nMP = fmaxf(tMP, tS + oMP);
            float nMN = fminf(tMN, tS + oMN);
            tS += oS; tMP = nMP; tMN = nMN; tDD = nDD;
        }
        if ((tid & 63) == 0) stup[tid >> 6] = make_float4(tS, tMP, tMN, tDD);
        __syncthreads();   // B2: stup visible + all LDS reads of this tile done

        if (tid == 0) {
            for (int w = 0; w < 8; ++w) {
                float4 b = stup[w];
                if (tt == 0 && w == 0) { bS = b.x; bMP = b.y; bMN = b.z; bDD = b.w; }
                else {
                    double nDD = fmax(fmax(bDD, (double)b.w), bMP - (bS + (double)b.z));
                    double nMP = fmax(bMP, bS + (double)b.y);
                    double nMN = fmin(bMN, bS + (double)b.z);
                    bS += (double)b.x; bMP = nMP; bMN = nMN; bDD = nDD;
                }
            }
        }
    }

    // ---- fold 9 scalar accumulators once ----
    for (int off = 1; off < 64; off <<= 1) {
        sum_r  += __shfl_down(sum_r,  off); sum_r2 += __shfl_down(sum_r2, off);
        sum_ab += __shfl_down(sum_ab, off); cnt_p  += __shfl_down(cnt_p,  off);
        sum_adr+= __shfl_down(sum_adr,off); sum_sgn+= __shfl_down(sum_sgn,off);
        sum_ads+= __shfl_down(sum_ads,off); vsum   += __shfl_down(vsum,   off);
        vsqr   += __shfl_down(vsqr,   off);
    }
    int wv = tid >> 6;
    if ((tid & 63) == 0) {
        sred[wv][0]=sum_r;  sred[wv][1]=sum_r2; sred[wv][2]=sum_ab;
        sred[wv][3]=cnt_p;  sred[wv][4]=sum_adr; sred[wv][5]=sum_sgn;
        sred[wv][6]=sum_ads; sred[wv][7]=vsum;   sred[wv][8]=vsqr;
    }
    __syncthreads();

    if (tid < 9) {
        float tot = 0.f;
        for (int w = 0; w < 8; ++w) tot += sred[w][tid];
        atomicAdd(&acc[tid], (double)tot);
    }
    if (tid == 0) {
        double2* dd2 = (double2*)ddt;
        dd2[2 * blockIdx.x]     = make_double2(bS, bMP);
        dd2[2 * blockIdx.x + 1] = make_double2(bMN, bDD);
    }
    // ---- single histogram flush per block ----
    for (int b = tid; b < NBINS; b += BS) {
        unsigned long long v = lh[b];
        if (v) atomicAdd(&hg[b], v);
    }
}

// ============ combine: drawdown tree + hist scan + CVaR + final formula ======
__global__ __launch_bounds__(CB) void k_combine(const double* __restrict__ acc,
                                                const unsigned long long* __restrict__ hg,
                                                const double* __restrict__ ddt,
                                                float* __restrict__ out)
{
    __shared__ double dS[NB_MAIN], dMP[NB_MAIN], dMN[NB_MAIN], dDD[NB_MAIN];
    __shared__ double dBS[CB];
    __shared__ unsigned scn[CB];
    __shared__ int s_edge;
    __shared__ unsigned s_cbelow, s_ce;

    const int t = threadIdx.x;

    // ---- A: drawdown ordered tree over 256 block tuples (double) ----
    if (t < NB_MAIN) {
        const double2* dd2 = (const double2*)ddt;
        double2 a0 = dd2[2 * t], a1 = dd2[2 * t + 1];
        dS[t] = a0.x; dMP[t] = a0.y; dMN[t] = a1.x; dDD[t] = a1.y;
    }
    __syncthreads();
    for (int off = 1; off < NB_MAIN; off <<= 1) {
        if (t < NB_MAIN && (t & (2 * off - 1)) == 0) {
            double aS=dS[t], aMP=dMP[t], aMN=dMN[t], aDD=dDD[t];
            double bS=dS[t+off], bMP=dMP[t+off], bMN=dMN[t+off], bDD=dDD[t+off];
            dDD[t] = fmax(fmax(aDD, bDD), aMP - (aS + bMN));
            dMP[t] = fmax(aMP, aS + bMP);
            dMN[t] = fmin(aMN, aS + bMN);
            dS[t]  = aS + bS;
        }
        __syncthreads();
    }
    // dDD[0] holds global max drawdown

    // ---- B: histogram scan (1 bin per thread) ----
    unsigned long long h = hg[t];
    unsigned cnt = (unsigned)(h >> CNT_SHIFT);
    double sum_bin = (double)(long long)(h & ((1ull << CNT_SHIFT) - 1ull)) * INV_FPSCALE
                   - 0.5 * (double)cnt;
    scn[t] = cnt;
    __syncthreads();
    for (int off = 1; off < CB; off <<= 1) {
        unsigned y = (t >= off) ? scn[t - off] : 0u;
        __syncthreads();
        scn[t] += y;
        __syncthreads();
    }
    unsigned incl = scn[t], excl = incl - cnt;
    if (excl < K_CVAR && incl >= K_CVAR) { s_edge = t; s_cbelow = excl; s_ce = cnt; }
    __syncthreads();
    const int be = s_edge;
    const unsigned cb = s_cbelow, ce = s_ce;

    // ---- C: sum of bin sums strictly below the edge bin ----
    dBS[t] = (t < be) ? sum_bin : 0.0;
    __syncthreads();
    for (int off = CB / 2; off >= 1; off >>= 1) {
        if (t < off) dBS[t] += dBS[t + off];
        __syncthreads();
    }

    if (t == 0) {
        double n = (double)N_TOTAL;
        double S1 = acc[0], S2 = acc[1], S3 = acc[2], S4 = acc[3];
        double S5 = acc[4], S6 = acc[5], S7 = acc[6], V1 = acc[7], V2 = acc[8];

        double mean_r = S1 / n;
        double var_r = (S2 - S1 * S1 / n) / (n - 1.0);
        if (var_r < 0.0) var_r = 0.0;
        double std_r = sqrt(var_r) + 1e-8;
        double base_sharpe = mean_r / std_r;

        double m = (double)M_ROLL;
        double var_v = (V2 - V1 * V1 / m) / (m - 1.0);
        if (var_v < 0.0) var_v = 0.0;
        double vs = 1.0 / (sqrt(var_v) + 1e-6);
        double es = base_sharpe * (1.0 + 0.1 * vs);

        double rm = S3 / n;
        double pf = S4 / n;
        double rs = 1.0 / (S5 / (n - 1.0) + 1e-6);
        double mc = S6 / (n - 1.0);
        double dd = fmax(dDD[0], 0.0);
        double ddp = dd - 0.05; if (ddp < 0.0) ddp = 0.0;
        double sc = S7 / (n - 1.0);
        double ss = 1.0 / (sc + 1e-6);

        // CVaR: full bins below edge + interpolated draw from the edge bin
        double bsum = dBS[0];
        double mneed = (double)(K_CVAR - cb);
        double elo = (double)inv_ordkey(((unsigned)be) << 22);
        double ehi = (double)inv_ordkey(((unsigned)(be + 1)) << 22);
        double edgev = elo + (mneed / (2.0 * (double)(ce > 0u ? ce : 1u))) * (ehi - elo);
        double cvar = -(bsum + mneed * edgev) / (double)K_CVAR;

        double SC = 0.4 * es + 0.25 * rm + 0.15 * pf + 0.1 * mc + 0.05 * rs + 0.05 * ss;
        double RP = 0.05 * cvar + 0.02 * ddp + 0.01 * sc;
        out[0] = (float)(-(0.6 * rm + 0.4 * SC - RP));
    }
}

// ============ launch =========================================================
extern "C" void kernel_launch(void* const* d_in, const int* in_sizes, int n_in,
                              void* d_out, int out_size, void* d_ws, size_t ws_size,
                              hipStream_t stream)
{
    const float* pred = (const float*)d_in[0];
    const float* ret  = (const float*)d_in[1];
    char* ws = (char*)d_ws;
    double*             acc = (double*)(ws + ACC_OFF);
    unsigned long long* hg  = (unsigned long long*)(ws + HG_OFF);
    double*             ddt = (double*)(ws + DDT_OFF);

    hipMemsetAsync(ws, 0, ZERO_BYTES, stream);
    k_main<<<NB_MAIN, BS, 0, stream>>>(pred, ret, acc, hg, ddt);
    k_combine<<<1, CB, 0, stream>>>(acc, hg, ddt, (float*)d_out);
}